// Round 20
// baseline (536.296 us; speedup 1.0000x reference)
//
#include <hip/hip_runtime.h>
#include <cstddef>

#define DD     256      // feature dim
#define NCODES 1024     // codebook size
#define MTOT   65536    // 8*8192 queries
#define MB     64       // rows per block (1024 blocks)

typedef __attribute__((ext_vector_type(8))) short short8v;  // 8 bf16 (4 VGPR)
typedef __attribute__((ext_vector_type(4))) float f32x4;    // MFMA accum

// ====== XLA:CPU f32 replica helpers (DO NOT TOUCH — verified r13) ==========
__device__ __forceinline__ float xla_seq_fma_sumsq256(const float* __restrict__ a) {
    float acc = 0.f;
    #pragma unroll 8
    for (int d = 0; d < 256; ++d)
        acc = __builtin_fmaf(a[d], a[d], acc);
    return acc;
}

__device__ __forceinline__ float chain_fma_dot256(const float* __restrict__ x,
                                                  const float* __restrict__ w) {
    float acc = 0.f;
    #pragma unroll 8
    for (int d = 0; d < 256; ++d)
        acc = __builtin_fmaf(x[d], w[d], acc);
    return acc;
}

// ====== bf16 helpers (screening only) ======================================
__device__ __forceinline__ short bf16_rne(float f) {
    unsigned u = __builtin_bit_cast(unsigned, f);
    u = u + 0x7FFFu + ((u >> 16) & 1u);
    return (short)(u >> 16);
}

// --- kernel 0a: per-code squared norms, XLA-replica bits -------------------
__global__ __launch_bounds__(256) void w2_kernel(const float* __restrict__ W,
                                                 float* __restrict__ w2) {
    int c = blockIdx.x * 256 + threadIdx.x;
    if (c >= NCODES) return;
    w2[c] = xla_seq_fma_sumsq256(W + (size_t)c * DD);
}

// --- kernel 0b: W -> bf16 once (coalesced; 65536 threads x 4 floats) -------
__global__ __launch_bounds__(256) void wprep_kernel(const float* __restrict__ W,
                                                    short* __restrict__ Wbf) {
    const int t = blockIdx.x * 256 + threadIdx.x;   // 0..65535
    const float4 v = *reinterpret_cast<const float4*>(W + (size_t)t * 4);
    short4 s;
    s.x = bf16_rne(v.x); s.y = bf16_rne(v.y);
    s.z = bf16_rne(v.z); s.w = bf16_rne(v.w);
    *reinterpret_cast<short4*>(Wbf + (size_t)t * 4) = s;
}

// insert (nv,ni) into sorted triple, keep smallest 3
__device__ __forceinline__ void ins3(float& v0, int& i0, float& v1, int& i1,
                                     float& v2, int& i2, float nv, int ni) {
    if (nv < v0) { v2 = v1; i2 = i1; v1 = v0; i1 = i0; v0 = nv; i0 = ni; }
    else if (nv < v1) { v2 = v1; i2 = i1; v1 = nv; i1 = ni; }
    else if (nv < v2) { v2 = nv; i2 = ni; }
}

// --- kernel 1: MFMA bf16 screening (L2-direct B) + top-3 + exact re-rank ---
// 64 rows/block, 4 waves; wave w owns rows w*16..+15 (K=256 A-frags in regs).
// B-fragments load DIRECTLY from the L2-resident bf16 codebook (512 KB) —
// no LDS staging, no barriers in the screening loop.
// mfma_f32_16x16x32_bf16 C/D: col=lane&15, row=(lane>>4)*4+reg (m89).
// amdgpu_waves_per_eu(2,4): cap the backend's occupancy target — r18/r19's
// 38.9 KB-LDS kernel made it target 8 waves/EU, allocate 60 VGPRs and spill
// 1.2 GB to scratch. Max=4 keeps the ~95 live VGPRs in registers.
__global__ __launch_bounds__(256)
__attribute__((amdgpu_waves_per_eu(2, 4)))
void vq_main(
    const float* __restrict__ X, const short* __restrict__ Wbf,
    const float* __restrict__ W, const float* __restrict__ w2g,
    float* __restrict__ out, float* __restrict__ dl)
{
    __shared__ float w2s[NCODES];
    __shared__ int   cand[MB][3];
    __shared__ int   idx_s[MB];

    const int tid  = threadIdx.x;
    const int lane = tid & 63;
    const int wv   = tid >> 6;
    const int m0   = blockIdx.x * MB;
    const int lg   = lane & 15;            // col-in-frag / row-in-frag
    const int kb   = (lane >> 4) * 8;      // k base within 32-chunk

    for (int i = tid; i < NCODES; i += 256) w2s[i] = w2g[i];

    // A-frags: this wave's 16 rows, full K=256 (8 frags of 8 bf16)
    const int arow = m0 + wv * 16 + lg;
    short8v a_frags[8];
    #pragma unroll
    for (int kg = 0; kg < 8; ++kg) {
        const float* src = X + (size_t)arow * DD + kg * 32 + kb;
        const float4 x0 = *reinterpret_cast<const float4*>(src);
        const float4 x1 = *reinterpret_cast<const float4*>(src + 4);
        short8v s;
        s[0] = bf16_rne(x0.x); s[1] = bf16_rne(x0.y);
        s[2] = bf16_rne(x0.z); s[3] = bf16_rne(x0.w);
        s[4] = bf16_rne(x1.x); s[5] = bf16_rne(x1.y);
        s[6] = bf16_rne(x1.z); s[7] = bf16_rne(x1.w);
        a_frags[kg] = s;
    }

    // per-lane top-3 per owned row-reg (rows (lane>>4)*4 + rg)
    float v[4][3]; int vi[4][3];
    #pragma unroll
    for (int rg = 0; rg < 4; ++rg)
        #pragma unroll
        for (int j = 0; j < 3; ++j) { v[rg][j] = 3.4e38f; vi[rg][j] = 0; }

    __syncthreads();   // w2s ready

    // screening: 64 groups of 16 codes, B-frags straight from L2
    for (int g = 0; g < NCODES / 16; ++g) {
        const int cbase = g * 16 + lg;     // this lane's code column
        const short* bp = Wbf + (size_t)cbase * DD + kb;
        f32x4 acc = {0.f, 0.f, 0.f, 0.f};
        #pragma unroll
        for (int kg = 0; kg < 8; ++kg) {
            const short8v b = *reinterpret_cast<const short8v*>(bp + kg * 32);
            acc = __builtin_amdgcn_mfma_f32_16x16x32_bf16(
                a_frags[kg], b, acc, 0, 0, 0);
        }
        const float w2v = w2s[cbase];
        #pragma unroll
        for (int rg = 0; rg < 4; ++rg) {
            const float d = __builtin_fmaf(-2.f, acc[rg], w2v);
            ins3(v[rg][0], vi[rg][0], v[rg][1], vi[rg][1],
                 v[rg][2], vi[rg][2], d, cbase);
        }
    }

    // shuffle top-3 merge across the 16 candidate lanes (lg) of each group
    #pragma unroll
    for (int rg = 0; rg < 4; ++rg) {
        #pragma unroll
        for (int m = 1; m <= 8; m <<= 1) {
            const float o0 = __shfl_xor(v[rg][0], m);
            const int   q0 = __shfl_xor(vi[rg][0], m);
            const float o1 = __shfl_xor(v[rg][1], m);
            const int   q1 = __shfl_xor(vi[rg][1], m);
            const float o2 = __shfl_xor(v[rg][2], m);
            const int   q2 = __shfl_xor(vi[rg][2], m);
            ins3(v[rg][0], vi[rg][0], v[rg][1], vi[rg][1], v[rg][2], vi[rg][2], o0, q0);
            ins3(v[rg][0], vi[rg][0], v[rg][1], vi[rg][1], v[rg][2], vi[rg][2], o1, q1);
            ins3(v[rg][0], vi[rg][0], v[rg][1], vi[rg][1], v[rg][2], vi[rg][2], o2, q2);
        }
        if (lg == 0) {
            const int r = wv * 16 + (lane >> 4) * 4 + rg;
            cand[r][0] = vi[rg][0];
            cand[r][1] = vi[rg][1];
            cand[r][2] = vi[rg][2];
        }
    }
    __syncthreads();

    // bit-exact re-rank over 3 candidates (r13 recipe), ascending index
    if (tid < MB) {
        int b0 = cand[tid][0], b1 = cand[tid][1], b2 = cand[tid][2];
        int t;
        if (b0 > b1) { t = b0; b0 = b1; b1 = t; }
        if (b1 > b2) { t = b1; b1 = b2; b2 = t; }
        if (b0 > b1) { t = b0; b0 = b1; b1 = t; }
        {
#pragma clang fp contract(off)
            const float* xr = X + (size_t)(m0 + tid) * DD;
            const float x2 = xla_seq_fma_sumsq256(xr);
            float best = 3.4e38f; int pick = b0; float pd = 0.f;
            const int cs[3] = {b0, b1, b2};
            #pragma unroll
            for (int u = 0; u < 3; ++u) {
                const int c = cs[u];
                const float xw = chain_fma_dot256(xr, W + (size_t)c * DD);
                const float dd = (x2 - 2.0f * xw) + w2s[c];
                if (dd < best) { best = dd; pick = c; pd = xw; }
            }
            idx_s[tid] = pick;
            dl[m0 + tid] = pd;
        }
    }
    __syncthreads();

    // gather-write quantized rows (coalesced float4)
    const float4* W4 = reinterpret_cast<const float4*>(W);
    float4*       O4 = reinterpret_cast<float4*>(out);
    #pragma unroll
    for (int l = 0; l < 16; ++l) {
        const int e  = tid + l * 256;   // 0..4095
        const int r  = e >> 6;
        const int c4 = e & 63;
        O4[(size_t)(m0 + r) * (DD / 4) + c4] =
            W4[(size_t)idx_s[r] * (DD / 4) + c4];
    }
}

// --- kernel 2a: per-batch softmax sum (8 blocks, one per batch) ------------
__global__ __launch_bounds__(256) void vq_loss_partial(const float* __restrict__ dl,
                                                       float* __restrict__ partial) {
    __shared__ float red[256];
    const int tid = threadIdx.x;
    const int b   = blockIdx.x;
    const float* row = dl + (size_t)b * 8192;

    float lm = -3.4e38f;
    for (int i = tid; i < 8192; i += 256) lm = fmaxf(lm, row[i]);
    red[tid] = lm; __syncthreads();
    for (int s = 128; s > 0; s >>= 1) {
        if (tid < s) red[tid] = fmaxf(red[tid], red[tid + s]);
        __syncthreads();
    }
    const float mx = red[0]; __syncthreads();

    float ls = 0.f;
    for (int i = tid; i < 8192; i += 256) ls += expf(row[i] - mx);
    red[tid] = ls; __syncthreads();
    for (int s = 128; s > 0; s >>= 1) {
        if (tid < s) red[tid] += red[tid + s];
        __syncthreads();
    }
    const float Z = red[0]; __syncthreads();

    float lc = 0.f;
    for (int i = tid; i < 8192; i += 256) lc += expf(row[i] - mx) / Z;
    red[tid] = lc; __syncthreads();
    for (int s = 128; s > 0; s >>= 1) {
        if (tid < s) red[tid] += red[tid + s];
        __syncthreads();
    }
    if (tid == 0) partial[b] = red[0];
}

// --- kernel 2b: final sum of 8 partials ------------------------------------
__global__ void vq_loss_final(const float* __restrict__ partial,
                              float* __restrict__ outv) {
    if (threadIdx.x == 0) {
        float t = 0.f;
        for (int b = 0; b < 8; ++b) t += partial[b];
        outv[0] = t;
    }
}

// --- launch ----------------------------------------------------------------
extern "C" void kernel_launch(void* const* d_in, const int* in_sizes, int n_in,
                              void* d_out, int out_size, void* d_ws, size_t ws_size,
                              hipStream_t stream) {
    const float* X = (const float*)d_in[0];   // latents  [8,8192,256] f32
    const float* W = (const float*)d_in[1];   // weights  [1024,256]   f32
    float* out = (float*)d_out;               // quantized (65536*256) + vq_loss
    float* w2      = (float*)d_ws;            // [1024]  XLA-replica code norms
    float* dlv     = w2 + NCODES;             // [65536] dot at argmin
    float* partial = dlv + MTOT;              // [8]     per-batch loss
    short* Wbf     = (short*)(partial + 8);   // [1024*256] bf16 codebook

    w2_kernel      <<<NCODES / 256,            256, 0, stream>>>(W, w2);
    wprep_kernel   <<<NCODES * DD / 4 / 256,   256, 0, stream>>>(W, Wbf);  // 256 blocks
    vq_main        <<<MTOT / MB,               256, 0, stream>>>(X, Wbf, W, w2, out, dlv);
    vq_loss_partial<<<8,                       256, 0, stream>>>(dlv, partial);
    vq_loss_final  <<<1,                        64, 0, stream>>>(partial, out + (size_t)MTOT * DD);
}

// Round 21
// 347.787 us; speedup vs baseline: 1.5420x; 1.5420x over previous
//
#include <hip/hip_runtime.h>
#include <cstddef>

#define DD     256      // feature dim
#define NCODES 1024     // codebook size
#define MTOT   65536    // 8*8192 queries
#define MB     64       // rows per block (1024 blocks)

typedef __attribute__((ext_vector_type(8))) short short8v;  // 8 bf16 (4 VGPR)
typedef __attribute__((ext_vector_type(4))) float f32x4;    // MFMA accum

// ====== XLA:CPU f32 replica helpers (DO NOT TOUCH — verified r13) ==========
__device__ __forceinline__ float xla_seq_fma_sumsq256(const float* __restrict__ a) {
    float acc = 0.f;
    #pragma unroll 8
    for (int d = 0; d < 256; ++d)
        acc = __builtin_fmaf(a[d], a[d], acc);
    return acc;
}

__device__ __forceinline__ float chain_fma_dot256(const float* __restrict__ x,
                                                  const float* __restrict__ w) {
    float acc = 0.f;
    #pragma unroll 8
    for (int d = 0; d < 256; ++d)
        acc = __builtin_fmaf(x[d], w[d], acc);
    return acc;
}

// ====== bf16 helpers (screening only) ======================================
__device__ __forceinline__ short bf16_rne(float f) {
    unsigned u = __builtin_bit_cast(unsigned, f);
    u = u + 0x7FFFu + ((u >> 16) & 1u);
    return (short)(u >> 16);
}

// --- kernel 0a: per-code squared norms, XLA-replica bits -------------------
__global__ __launch_bounds__(256) void w2_kernel(const float* __restrict__ W,
                                                 float* __restrict__ w2) {
    int c = blockIdx.x * 256 + threadIdx.x;
    if (c >= NCODES) return;
    w2[c] = xla_seq_fma_sumsq256(W + (size_t)c * DD);
}

// --- kernel 0b: W -> bf16 once (coalesced; 65536 threads x 4 floats) -------
__global__ __launch_bounds__(256) void wprep_kernel(const float* __restrict__ W,
                                                    short* __restrict__ Wbf) {
    const int t = blockIdx.x * 256 + threadIdx.x;   // 0..65535
    const float4 v = *reinterpret_cast<const float4*>(W + (size_t)t * 4);
    short4 s;
    s.x = bf16_rne(v.x); s.y = bf16_rne(v.y);
    s.z = bf16_rne(v.z); s.w = bf16_rne(v.w);
    *reinterpret_cast<short4*>(Wbf + (size_t)t * 4) = s;
}

// Scalar top-3 insert as a STATEMENT MACRO — no references, no arrays:
// r17-r20's ins3(float&,...) helper forced the v/vi arrays into scratch
// (1.2 GB spill traffic, 4.6 KB/thread = 64 iters x 72 B rewritten).
#define INS3(V0,I0,V1,I1,V2,I2,NV,NI) do {                              \
    const float _nv = (NV); const int _ni = (NI);                       \
    if (_nv < (V0))      { (V2)=(V1); (I2)=(I1); (V1)=(V0); (I1)=(I0); \
                           (V0)=_nv;  (I0)=_ni; }                       \
    else if (_nv < (V1)) { (V2)=(V1); (I2)=(I1); (V1)=_nv; (I1)=_ni; }  \
    else if (_nv < (V2)) { (V2)=_nv;  (I2)=_ni; }                       \
} while (0)

// shuffle-merge one triple across lanes (xor m), inserting other's 3
#define MERGE3(V0,I0,V1,I1,V2,I2,M) do {                                \
    const float _o0 = __shfl_xor((V0), (M));                            \
    const int   _q0 = __shfl_xor((I0), (M));                            \
    const float _o1 = __shfl_xor((V1), (M));                            \
    const int   _q1 = __shfl_xor((I1), (M));                            \
    const float _o2 = __shfl_xor((V2), (M));                            \
    const int   _q2 = __shfl_xor((I2), (M));                            \
    INS3(V0,I0,V1,I1,V2,I2,_o0,_q0);                                    \
    INS3(V0,I0,V1,I1,V2,I2,_o1,_q1);                                    \
    INS3(V0,I0,V1,I1,V2,I2,_o2,_q2);                                    \
} while (0)

// --- kernel 1: MFMA bf16 screening (L2-direct B) + top-3 + exact re-rank ---
// 64 rows/block, 4 waves; wave w owns rows w*16..+15 (K=256 A-frags in regs).
// B-fragments load directly from the L2-resident bf16 codebook (512 KB) —
// no LDS staging, no barriers in the screening loop.
// mfma_f32_16x16x32_bf16 C/D: col=lane&15, row=(lane>>4)*4+reg (m89).
__global__ __launch_bounds__(256, 2) void vq_main(
    const float* __restrict__ X, const short* __restrict__ Wbf,
    const float* __restrict__ W, const float* __restrict__ w2g,
    float* __restrict__ out, float* __restrict__ dl)
{
    __shared__ float w2s[NCODES];
    __shared__ int   cand[MB][3];
    __shared__ int   idx_s[MB];

    const int tid  = threadIdx.x;
    const int lane = tid & 63;
    const int wv   = tid >> 6;
    const int m0   = blockIdx.x * MB;
    const int lg   = lane & 15;            // col-in-frag / row-in-frag
    const int kb   = (lane >> 4) * 8;      // k base within 32-chunk

    for (int i = tid; i < NCODES; i += 256) w2s[i] = w2g[i];

    // A-frags: this wave's 16 rows, full K=256 (8 frags of 8 bf16)
    const int arow = m0 + wv * 16 + lg;
    short8v a_frags[8];
    #pragma unroll
    for (int kg = 0; kg < 8; ++kg) {
        const float* src = X + (size_t)arow * DD + kg * 32 + kb;
        const float4 x0 = *reinterpret_cast<const float4*>(src);
        const float4 x1 = *reinterpret_cast<const float4*>(src + 4);
        short8v s;
        s[0] = bf16_rne(x0.x); s[1] = bf16_rne(x0.y);
        s[2] = bf16_rne(x0.z); s[3] = bf16_rne(x0.w);
        s[4] = bf16_rne(x1.x); s[5] = bf16_rne(x1.y);
        s[6] = bf16_rne(x1.z); s[7] = bf16_rne(x1.w);
        a_frags[kg] = s;
    }

    // per-lane top-3 per owned row-reg, as NAMED SCALARS (no arrays)
    float v0_0 = 3.4e38f, v1_0 = 3.4e38f, v2_0 = 3.4e38f;
    float v0_1 = 3.4e38f, v1_1 = 3.4e38f, v2_1 = 3.4e38f;
    float v0_2 = 3.4e38f, v1_2 = 3.4e38f, v2_2 = 3.4e38f;
    float v0_3 = 3.4e38f, v1_3 = 3.4e38f, v2_3 = 3.4e38f;
    int   i0_0 = 0, i1_0 = 0, i2_0 = 0;
    int   i0_1 = 0, i1_1 = 0, i2_1 = 0;
    int   i0_2 = 0, i1_2 = 0, i2_2 = 0;
    int   i0_3 = 0, i1_3 = 0, i2_3 = 0;

    __syncthreads();   // w2s ready

    // screening: 64 groups of 16 codes, B-frags straight from L2
    for (int g = 0; g < NCODES / 16; ++g) {
        const int cbase = g * 16 + lg;     // this lane's code column
        const short* bp = Wbf + (size_t)cbase * DD + kb;
        f32x4 acc = {0.f, 0.f, 0.f, 0.f};
        #pragma unroll
        for (int kg = 0; kg < 8; ++kg) {
            const short8v b = *reinterpret_cast<const short8v*>(bp + kg * 32);
            acc = __builtin_amdgcn_mfma_f32_16x16x32_bf16(
                a_frags[kg], b, acc, 0, 0, 0);
        }
        const float w2v = w2s[cbase];
        const float d0 = __builtin_fmaf(-2.f, acc[0], w2v);
        const float d1 = __builtin_fmaf(-2.f, acc[1], w2v);
        const float d2 = __builtin_fmaf(-2.f, acc[2], w2v);
        const float d3 = __builtin_fmaf(-2.f, acc[3], w2v);
        INS3(v0_0, i0_0, v1_0, i1_0, v2_0, i2_0, d0, cbase);
        INS3(v0_1, i0_1, v1_1, i1_1, v2_1, i2_1, d1, cbase);
        INS3(v0_2, i0_2, v1_2, i1_2, v2_2, i2_2, d2, cbase);
        INS3(v0_3, i0_3, v1_3, i1_3, v2_3, i2_3, d3, cbase);
    }

    // shuffle top-3 merge across the 16 candidate lanes (lg) of each group
    #pragma unroll
    for (int m = 1; m <= 8; m <<= 1) {
        MERGE3(v0_0, i0_0, v1_0, i1_0, v2_0, i2_0, m);
        MERGE3(v0_1, i0_1, v1_1, i1_1, v2_1, i2_1, m);
        MERGE3(v0_2, i0_2, v1_2, i1_2, v2_2, i2_2, m);
        MERGE3(v0_3, i0_3, v1_3, i1_3, v2_3, i2_3, m);
    }
    if (lg == 0) {
        const int rb = wv * 16 + (lane >> 4) * 4;
        cand[rb + 0][0] = i0_0; cand[rb + 0][1] = i1_0; cand[rb + 0][2] = i2_0;
        cand[rb + 1][0] = i0_1; cand[rb + 1][1] = i1_1; cand[rb + 1][2] = i2_1;
        cand[rb + 2][0] = i0_2; cand[rb + 2][1] = i1_2; cand[rb + 2][2] = i2_2;
        cand[rb + 3][0] = i0_3; cand[rb + 3][1] = i1_3; cand[rb + 3][2] = i2_3;
    }
    __syncthreads();

    // bit-exact re-rank over 3 candidates (r13 recipe), ascending index
    if (tid < MB) {
        int b0 = cand[tid][0], b1 = cand[tid][1], b2 = cand[tid][2];
        int t;
        if (b0 > b1) { t = b0; b0 = b1; b1 = t; }
        if (b1 > b2) { t = b1; b1 = b2; b2 = t; }
        if (b0 > b1) { t = b0; b0 = b1; b1 = t; }
        {
#pragma clang fp contract(off)
            const float* xr = X + (size_t)(m0 + tid) * DD;
            const float x2 = xla_seq_fma_sumsq256(xr);
            const float xw0 = chain_fma_dot256(xr, W + (size_t)b0 * DD);
            const float xw1 = chain_fma_dot256(xr, W + (size_t)b1 * DD);
            const float xw2 = chain_fma_dot256(xr, W + (size_t)b2 * DD);
            const float dd0 = (x2 - 2.0f * xw0) + w2s[b0];
            const float dd1 = (x2 - 2.0f * xw1) + w2s[b1];
            const float dd2 = (x2 - 2.0f * xw2) + w2s[b2];
            int pick = b0; float best = dd0; float pd = xw0;
            if (dd1 < best) { best = dd1; pick = b1; pd = xw1; }
            if (dd2 < best) { best = dd2; pick = b2; pd = xw2; }
            idx_s[tid] = pick;
            dl[m0 + tid] = pd;
        }
    }
    __syncthreads();

    // gather-write quantized rows (coalesced float4)
    const float4* W4 = reinterpret_cast<const float4*>(W);
    float4*       O4 = reinterpret_cast<float4*>(out);
    #pragma unroll
    for (int l = 0; l < 16; ++l) {
        const int e  = tid + l * 256;   // 0..4095
        const int r  = e >> 6;
        const int c4 = e & 63;
        O4[(size_t)(m0 + r) * (DD / 4) + c4] =
            W4[(size_t)idx_s[r] * (DD / 4) + c4];
    }
}

// --- kernel 2a: per-batch softmax sum (8 blocks, one per batch) ------------
__global__ __launch_bounds__(256) void vq_loss_partial(const float* __restrict__ dl,
                                                       float* __restrict__ partial) {
    __shared__ float red[256];
    const int tid = threadIdx.x;
    const int b   = blockIdx.x;
    const float* row = dl + (size_t)b * 8192;

    float lm = -3.4e38f;
    for (int i = tid; i < 8192; i += 256) lm = fmaxf(lm, row[i]);
    red[tid] = lm; __syncthreads();
    for (int s = 128; s > 0; s >>= 1) {
        if (tid < s) red[tid] = fmaxf(red[tid], red[tid + s]);
        __syncthreads();
    }
    const float mx = red[0]; __syncthreads();

    float ls = 0.f;
    for (int i = tid; i < 8192; i += 256) ls += expf(row[i] - mx);
    red[tid] = ls; __syncthreads();
    for (int s = 128; s > 0; s >>= 1) {
        if (tid < s) red[tid] += red[tid + s];
        __syncthreads();
    }
    const float Z = red[0]; __syncthreads();

    float lc = 0.f;
    for (int i = tid; i < 8192; i += 256) lc += expf(row[i] - mx) / Z;
    red[tid] = lc; __syncthreads();
    for (int s = 128; s > 0; s >>= 1) {
        if (tid < s) red[tid] += red[tid + s];
        __syncthreads();
    }
    if (tid == 0) partial[b] = red[0];
}

// --- kernel 2b: final sum of 8 partials ------------------------------------
__global__ void vq_loss_final(const float* __restrict__ partial,
                              float* __restrict__ outv) {
    if (threadIdx.x == 0) {
        float t = 0.f;
        for (int b = 0; b < 8; ++b) t += partial[b];
        outv[0] = t;
    }
}

// --- launch ----------------------------------------------------------------
extern "C" void kernel_launch(void* const* d_in, const int* in_sizes, int n_in,
                              void* d_out, int out_size, void* d_ws, size_t ws_size,
                              hipStream_t stream) {
    const float* X = (const float*)d_in[0];   // latents  [8,8192,256] f32
    const float* W = (const float*)d_in[1];   // weights  [1024,256]   f32
    float* out = (float*)d_out;               // quantized (65536*256) + vq_loss
    float* w2      = (float*)d_ws;            // [1024]  XLA-replica code norms
    float* dlv     = w2 + NCODES;             // [65536] dot at argmin
    float* partial = dlv + MTOT;              // [8]     per-batch loss
    short* Wbf     = (short*)(partial + 8);   // [1024*256] bf16 codebook

    w2_kernel      <<<NCODES / 256,            256, 0, stream>>>(W, w2);
    wprep_kernel   <<<NCODES * DD / 4 / 256,   256, 0, stream>>>(W, Wbf);  // 256 blocks
    vq_main        <<<MTOT / MB,               256, 0, stream>>>(X, Wbf, W, w2, out, dlv);
    vq_loss_partial<<<8,                       256, 0, stream>>>(dlv, partial);
    vq_loss_final  <<<1,                        64, 0, stream>>>(partial, out + (size_t)MTOT * DD);
}

// Round 22
// 216.286 us; speedup vs baseline: 2.4796x; 1.6080x over previous
//
#include <hip/hip_runtime.h>
#include <cstddef>

#define DD     256      // feature dim
#define NCODES 1024     // codebook size
#define MTOT   65536    // 8*8192 queries
#define MB     64       // rows per block (1024 blocks)
#define WSTR   264      // Wl LDS row stride in bf16 units (256 + 8 pad)

typedef __attribute__((ext_vector_type(8))) short short8v;  // 8 bf16 (4 VGPR)
typedef __attribute__((ext_vector_type(4))) float f32x4;    // MFMA accum

// ====== XLA:CPU f32 replica helpers (DO NOT TOUCH — verified r13) ==========
__device__ __forceinline__ float xla_seq_fma_sumsq256(const float* __restrict__ a) {
    float acc = 0.f;
    #pragma unroll 8
    for (int d = 0; d < 256; ++d)
        acc = __builtin_fmaf(a[d], a[d], acc);
    return acc;
}

__device__ __forceinline__ float chain_fma_dot256(const float* __restrict__ x,
                                                  const float* __restrict__ w) {
    float acc = 0.f;
    #pragma unroll 8
    for (int d = 0; d < 256; ++d)
        acc = __builtin_fmaf(x[d], w[d], acc);
    return acc;
}

// ====== bf16 helpers (screening only) ======================================
__device__ __forceinline__ short bf16_rne(float f) {
    unsigned u = __builtin_bit_cast(unsigned, f);
    u = u + 0x7FFFu + ((u >> 16) & 1u);
    return (short)(u >> 16);
}

// --- kernel 0a: per-code squared norms, XLA-replica bits -------------------
__global__ __launch_bounds__(256) void w2_kernel(const float* __restrict__ W,
                                                 float* __restrict__ w2) {
    int c = blockIdx.x * 256 + threadIdx.x;
    if (c >= NCODES) return;
    w2[c] = xla_seq_fma_sumsq256(W + (size_t)c * DD);
}

// --- kernel 0b: W -> bf16 once (coalesced; 65536 threads x 4 floats) -------
__global__ __launch_bounds__(256) void wprep_kernel(const float* __restrict__ W,
                                                    short* __restrict__ Wbf) {
    const int t = blockIdx.x * 256 + threadIdx.x;   // 0..65535
    const float4 v = *reinterpret_cast<const float4*>(W + (size_t)t * 4);
    short4 s;
    s.x = bf16_rne(v.x); s.y = bf16_rne(v.y);
    s.z = bf16_rne(v.z); s.w = bf16_rne(v.w);
    *reinterpret_cast<short4*>(Wbf + (size_t)t * 4) = s;
}

// Scalar top-3 insert as a STATEMENT MACRO — no references, no arrays
// (r17-r20's ins3(float&) helper put the triples in scratch: 1.2 GB spill).
#define INS3(V0,I0,V1,I1,V2,I2,NV,NI) do {                              \
    const float _nv = (NV); const int _ni = (NI);                       \
    if (_nv < (V0))      { (V2)=(V1); (I2)=(I1); (V1)=(V0); (I1)=(I0); \
                           (V0)=_nv;  (I0)=_ni; }                       \
    else if (_nv < (V1)) { (V2)=(V1); (I2)=(I1); (V1)=_nv; (I1)=_ni; }  \
    else if (_nv < (V2)) { (V2)=_nv;  (I2)=_ni; }                       \
} while (0)

#define MERGE3(V0,I0,V1,I1,V2,I2,M) do {                                \
    const float _o0 = __shfl_xor((V0), (M));                            \
    const int   _q0 = __shfl_xor((I0), (M));                            \
    const float _o1 = __shfl_xor((V1), (M));                            \
    const int   _q1 = __shfl_xor((I1), (M));                            \
    const float _o2 = __shfl_xor((V2), (M));                            \
    const int   _q2 = __shfl_xor((I2), (M));                            \
    INS3(V0,I0,V1,I1,V2,I2,_o0,_q0);                                    \
    INS3(V0,I0,V1,I1,V2,I2,_o1,_q1);                                    \
    INS3(V0,I0,V1,I1,V2,I2,_o2,_q2);                                    \
} while (0)

// --- kernel 1: MFMA bf16 screening (LDS-staged B) + top-3 + exact re-rank --
// 64 rows/block, 4 waves; wave w owns rows w*16..+15 (K=256 A-frags in regs).
// Codes in 64-wide bf16 LDS tiles copied from the PRE-CONVERTED codebook
// (pure uint4 -> ds_write_b128, 16 instr/thread/tile). Per-block L2 read of
// Wbf = 512 KB (vs per-WAVE in r21's L2-direct: 4x less, and B-frag reads
// become ~12-cyc ds_read_b128 instead of ~200-cyc L2 loads).
// mfma_f32_16x16x32_bf16 C/D: col=lane&15, row=(lane>>4)*4+reg (m89).
__global__ __launch_bounds__(256, 2) void vq_main(
    const float* __restrict__ X, const short* __restrict__ Wbf,
    const float* __restrict__ W, const float* __restrict__ w2g,
    float* __restrict__ out, float* __restrict__ dl)
{
    __shared__ short Wl[64 * WSTR];        // bf16 W tile [code][d]
    __shared__ float w2s[NCODES];
    __shared__ int   cand[MB][3];
    __shared__ int   idx_s[MB];

    const int tid  = threadIdx.x;
    const int lane = tid & 63;
    const int wv   = tid >> 6;
    const int m0   = blockIdx.x * MB;
    const int lg   = lane & 15;            // col-in-frag / row-in-frag
    const int kb   = (lane >> 4) * 8;      // k base within 32-chunk

    for (int i = tid; i < NCODES; i += 256) w2s[i] = w2g[i];

    // A-frags: this wave's 16 rows, full K=256 (8 frags of 8 bf16)
    const int arow = m0 + wv * 16 + lg;
    short8v a_frags[8];
    #pragma unroll
    for (int kg = 0; kg < 8; ++kg) {
        const float* src = X + (size_t)arow * DD + kg * 32 + kb;
        const float4 x0 = *reinterpret_cast<const float4*>(src);
        const float4 x1 = *reinterpret_cast<const float4*>(src + 4);
        short8v s;
        s[0] = bf16_rne(x0.x); s[1] = bf16_rne(x0.y);
        s[2] = bf16_rne(x0.z); s[3] = bf16_rne(x0.w);
        s[4] = bf16_rne(x1.x); s[5] = bf16_rne(x1.y);
        s[6] = bf16_rne(x1.z); s[7] = bf16_rne(x1.w);
        a_frags[kg] = s;
    }

    // per-lane top-3 per owned row-reg, as NAMED SCALARS (no arrays)
    float v0_0 = 3.4e38f, v1_0 = 3.4e38f, v2_0 = 3.4e38f;
    float v0_1 = 3.4e38f, v1_1 = 3.4e38f, v2_1 = 3.4e38f;
    float v0_2 = 3.4e38f, v1_2 = 3.4e38f, v2_2 = 3.4e38f;
    float v0_3 = 3.4e38f, v1_3 = 3.4e38f, v2_3 = 3.4e38f;
    int   i0_0 = 0, i1_0 = 0, i2_0 = 0;
    int   i0_1 = 0, i1_1 = 0, i2_1 = 0;
    int   i0_2 = 0, i1_2 = 0, i2_2 = 0;
    int   i0_3 = 0, i1_3 = 0, i2_3 = 0;

    for (int ct = 0; ct < NCODES / 64; ++ct) {
        const int c0 = ct * 64;
        __syncthreads();   // protect previous tile's readers (and w2s, iter 0)
        // stage bf16 W tile (64 codes x 256 d): pure b128 copy, 8/thread
        #pragma unroll
        for (int l = 0; l < 8; ++l) {
            const int f    = tid + l * 256;   // 0..2047 16B-chunks
            const int code = f >> 5;          // 32 chunks per code
            const int ch   = f & 31;
            const uint4 wv4 = *reinterpret_cast<const uint4*>(
                Wbf + (size_t)(c0 + code) * DD + ch * 8);
            *reinterpret_cast<uint4*>(&Wl[code * WSTR + ch * 8]) = wv4;
        }
        __syncthreads();

        f32x4 acc0 = {0.f, 0.f, 0.f, 0.f};
        f32x4 acc1 = {0.f, 0.f, 0.f, 0.f};
        f32x4 acc2 = {0.f, 0.f, 0.f, 0.f};
        f32x4 acc3 = {0.f, 0.f, 0.f, 0.f};

        #pragma unroll
        for (int kg = 0; kg < 8; ++kg) {
            const short8v b0 = *reinterpret_cast<const short8v*>(
                &Wl[(0 * 16 + lg) * WSTR + kg * 32 + kb]);
            const short8v b1 = *reinterpret_cast<const short8v*>(
                &Wl[(1 * 16 + lg) * WSTR + kg * 32 + kb]);
            const short8v b2 = *reinterpret_cast<const short8v*>(
                &Wl[(2 * 16 + lg) * WSTR + kg * 32 + kb]);
            const short8v b3 = *reinterpret_cast<const short8v*>(
                &Wl[(3 * 16 + lg) * WSTR + kg * 32 + kb]);
            acc0 = __builtin_amdgcn_mfma_f32_16x16x32_bf16(a_frags[kg], b0, acc0, 0, 0, 0);
            acc1 = __builtin_amdgcn_mfma_f32_16x16x32_bf16(a_frags[kg], b1, acc1, 0, 0, 0);
            acc2 = __builtin_amdgcn_mfma_f32_16x16x32_bf16(a_frags[kg], b2, acc2, 0, 0, 0);
            acc3 = __builtin_amdgcn_mfma_f32_16x16x32_bf16(a_frags[kg], b3, acc3, 0, 0, 0);
        }

        // epilogue: dist = w2 - 2*xw, top-3 insert (4 codes per lane)
        {
            const int  c    = c0 + 0 * 16 + lg;
            const float w2v = w2s[c];
            INS3(v0_0, i0_0, v1_0, i1_0, v2_0, i2_0, __builtin_fmaf(-2.f, acc0[0], w2v), c);
            INS3(v0_1, i0_1, v1_1, i1_1, v2_1, i2_1, __builtin_fmaf(-2.f, acc0[1], w2v), c);
            INS3(v0_2, i0_2, v1_2, i1_2, v2_2, i2_2, __builtin_fmaf(-2.f, acc0[2], w2v), c);
            INS3(v0_3, i0_3, v1_3, i1_3, v2_3, i2_3, __builtin_fmaf(-2.f, acc0[3], w2v), c);
        }
        {
            const int  c    = c0 + 1 * 16 + lg;
            const float w2v = w2s[c];
            INS3(v0_0, i0_0, v1_0, i1_0, v2_0, i2_0, __builtin_fmaf(-2.f, acc1[0], w2v), c);
            INS3(v0_1, i0_1, v1_1, i1_1, v2_1, i2_1, __builtin_fmaf(-2.f, acc1[1], w2v), c);
            INS3(v0_2, i0_2, v1_2, i1_2, v2_2, i2_2, __builtin_fmaf(-2.f, acc1[2], w2v), c);
            INS3(v0_3, i0_3, v1_3, i1_3, v2_3, i2_3, __builtin_fmaf(-2.f, acc1[3], w2v), c);
        }
        {
            const int  c    = c0 + 2 * 16 + lg;
            const float w2v = w2s[c];
            INS3(v0_0, i0_0, v1_0, i1_0, v2_0, i2_0, __builtin_fmaf(-2.f, acc2[0], w2v), c);
            INS3(v0_1, i0_1, v1_1, i1_1, v2_1, i2_1, __builtin_fmaf(-2.f, acc2[1], w2v), c);
            INS3(v0_2, i0_2, v1_2, i1_2, v2_2, i2_2, __builtin_fmaf(-2.f, acc2[2], w2v), c);
            INS3(v0_3, i0_3, v1_3, i1_3, v2_3, i2_3, __builtin_fmaf(-2.f, acc2[3], w2v), c);
        }
        {
            const int  c    = c0 + 3 * 16 + lg;
            const float w2v = w2s[c];
            INS3(v0_0, i0_0, v1_0, i1_0, v2_0, i2_0, __builtin_fmaf(-2.f, acc3[0], w2v), c);
            INS3(v0_1, i0_1, v1_1, i1_1, v2_1, i2_1, __builtin_fmaf(-2.f, acc3[1], w2v), c);
            INS3(v0_2, i0_2, v1_2, i1_2, v2_2, i2_2, __builtin_fmaf(-2.f, acc3[2], w2v), c);
            INS3(v0_3, i0_3, v1_3, i1_3, v2_3, i2_3, __builtin_fmaf(-2.f, acc3[3], w2v), c);
        }
    }

    // shuffle top-3 merge across the 16 candidate lanes (lg) of each group
    #pragma unroll
    for (int m = 1; m <= 8; m <<= 1) {
        MERGE3(v0_0, i0_0, v1_0, i1_0, v2_0, i2_0, m);
        MERGE3(v0_1, i0_1, v1_1, i1_1, v2_1, i2_1, m);
        MERGE3(v0_2, i0_2, v1_2, i1_2, v2_2, i2_2, m);
        MERGE3(v0_3, i0_3, v1_3, i1_3, v2_3, i2_3, m);
    }
    if (lg == 0) {
        const int rb = wv * 16 + (lane >> 4) * 4;
        cand[rb + 0][0] = i0_0; cand[rb + 0][1] = i1_0; cand[rb + 0][2] = i2_0;
        cand[rb + 1][0] = i0_1; cand[rb + 1][1] = i1_1; cand[rb + 1][2] = i2_1;
        cand[rb + 2][0] = i0_2; cand[rb + 2][1] = i1_2; cand[rb + 2][2] = i2_2;
        cand[rb + 3][0] = i0_3; cand[rb + 3][1] = i1_3; cand[rb + 3][2] = i2_3;
    }
    __syncthreads();

    // bit-exact re-rank over 3 candidates (r13 recipe), ascending index
    if (tid < MB) {
        int b0 = cand[tid][0], b1 = cand[tid][1], b2 = cand[tid][2];
        int t;
        if (b0 > b1) { t = b0; b0 = b1; b1 = t; }
        if (b1 > b2) { t = b1; b1 = b2; b2 = t; }
        if (b0 > b1) { t = b0; b0 = b1; b1 = t; }
        {
#pragma clang fp contract(off)
            const float* xr = X + (size_t)(m0 + tid) * DD;
            const float x2 = xla_seq_fma_sumsq256(xr);
            const float xw0 = chain_fma_dot256(xr, W + (size_t)b0 * DD);
            const float xw1 = chain_fma_dot256(xr, W + (size_t)b1 * DD);
            const float xw2 = chain_fma_dot256(xr, W + (size_t)b2 * DD);
            const float dd0 = (x2 - 2.0f * xw0) + w2s[b0];
            const float dd1 = (x2 - 2.0f * xw1) + w2s[b1];
            const float dd2 = (x2 - 2.0f * xw2) + w2s[b2];
            int pick = b0; float best = dd0; float pd = xw0;
            if (dd1 < best) { best = dd1; pick = b1; pd = xw1; }
            if (dd2 < best) { best = dd2; pick = b2; pd = xw2; }
            idx_s[tid] = pick;
            dl[m0 + tid] = pd;
        }
    }
    __syncthreads();

    // gather-write quantized rows (coalesced float4)
    const float4* W4 = reinterpret_cast<const float4*>(W);
    float4*       O4 = reinterpret_cast<float4*>(out);
    #pragma unroll
    for (int l = 0; l < 16; ++l) {
        const int e  = tid + l * 256;   // 0..4095
        const int r  = e >> 6;
        const int c4 = e & 63;
        O4[(size_t)(m0 + r) * (DD / 4) + c4] =
            W4[(size_t)idx_s[r] * (DD / 4) + c4];
    }
}

// --- kernel 2a: per-batch softmax sum (8 blocks, one per batch) ------------
__global__ __launch_bounds__(256) void vq_loss_partial(const float* __restrict__ dl,
                                                       float* __restrict__ partial) {
    __shared__ float red[256];
    const int tid = threadIdx.x;
    const int b   = blockIdx.x;
    const float* row = dl + (size_t)b * 8192;

    float lm = -3.4e38f;
    for (int i = tid; i < 8192; i += 256) lm = fmaxf(lm, row[i]);
    red[tid] = lm; __syncthreads();
    for (int s = 128; s > 0; s >>= 1) {
        if (tid < s) red[tid] = fmaxf(red[tid], red[tid + s]);
        __syncthreads();
    }
    const float mx = red[0]; __syncthreads();

    float ls = 0.f;
    for (int i = tid; i < 8192; i += 256) ls += expf(row[i] - mx);
    red[tid] = ls; __syncthreads();
    for (int s = 128; s > 0; s >>= 1) {
        if (tid < s) red[tid] += red[tid + s];
        __syncthreads();
    }
    const float Z = red[0]; __syncthreads();

    float lc = 0.f;
    for (int i = tid; i < 8192; i += 256) lc += expf(row[i] - mx) / Z;
    red[tid] = lc; __syncthreads();
    for (int s = 128; s > 0; s >>= 1) {
        if (tid < s) red[tid] += red[tid + s];
        __syncthreads();
    }
    if (tid == 0) partial[b] = red[0];
}

// --- kernel 2b: final sum of 8 partials ------------------------------------
__global__ void vq_loss_final(const float* __restrict__ partial,
                              float* __restrict__ outv) {
    if (threadIdx.x == 0) {
        float t = 0.f;
        for (int b = 0; b < 8; ++b) t += partial[b];
        outv[0] = t;
    }
}

// --- launch ----------------------------------------------------------------
extern "C" void kernel_launch(void* const* d_in, const int* in_sizes, int n_in,
                              void* d_out, int out_size, void* d_ws, size_t ws_size,
                              hipStream_t stream) {
    const float* X = (const float*)d_in[0];   // latents  [8,8192,256] f32
    const float* W = (const float*)d_in[1];   // weights  [1024,256]   f32
    float* out = (float*)d_out;               // quantized (65536*256) + vq_loss
    float* w2      = (float*)d_ws;            // [1024]  XLA-replica code norms
    float* dlv     = w2 + NCODES;             // [65536] dot at argmin
    float* partial = dlv + MTOT;              // [8]     per-batch loss
    short* Wbf     = (short*)(partial + 8);   // [1024*256] bf16 codebook

    w2_kernel      <<<NCODES / 256,            256, 0, stream>>>(W, w2);
    wprep_kernel   <<<NCODES * DD / 4 / 256,   256, 0, stream>>>(W, Wbf);  // 256 blocks
    vq_main        <<<MTOT / MB,               256, 0, stream>>>(X, Wbf, W, w2, out, dlv);
    vq_loss_partial<<<8,                       256, 0, stream>>>(dlv, partial);
    vq_loss_final  <<<1,                        64, 0, stream>>>(partial, out + (size_t)MTOT * DD);
}

// Round 23
// 184.280 us; speedup vs baseline: 2.9102x; 1.1737x over previous
//
#include <hip/hip_runtime.h>
#include <cstddef>

#define DD     256      // feature dim
#define NCODES 1024     // codebook size
#define MTOT   65536    // 8*8192 queries
#define MB     128      // rows per block (512 blocks); each wave owns 32 rows
#define WSTR   264      // Wl LDS row stride in bf16 units (256 + 8 pad)

typedef __attribute__((ext_vector_type(8))) short short8v;  // 8 bf16 (4 VGPR)
typedef __attribute__((ext_vector_type(4))) float f32x4;    // MFMA accum

// ====== XLA:CPU f32 replica helpers (DO NOT TOUCH — verified r13) ==========
__device__ __forceinline__ float xla_seq_fma_sumsq256(const float* __restrict__ a) {
    float acc = 0.f;
    #pragma unroll 8
    for (int d = 0; d < 256; ++d)
        acc = __builtin_fmaf(a[d], a[d], acc);
    return acc;
}

__device__ __forceinline__ float chain_fma_dot256(const float* __restrict__ x,
                                                  const float* __restrict__ w) {
    float acc = 0.f;
    #pragma unroll 8
    for (int d = 0; d < 256; ++d)
        acc = __builtin_fmaf(x[d], w[d], acc);
    return acc;
}

// ====== bf16 helpers (screening only) ======================================
__device__ __forceinline__ short bf16_rne(float f) {
    unsigned u = __builtin_bit_cast(unsigned, f);
    u = u + 0x7FFFu + ((u >> 16) & 1u);
    return (short)(u >> 16);
}

// --- kernel 0a: per-code squared norms, XLA-replica bits -------------------
__global__ __launch_bounds__(256) void w2_kernel(const float* __restrict__ W,
                                                 float* __restrict__ w2) {
    int c = blockIdx.x * 256 + threadIdx.x;
    if (c >= NCODES) return;
    w2[c] = xla_seq_fma_sumsq256(W + (size_t)c * DD);
}

// --- kernel 0b: W -> bf16 once (coalesced; 65536 threads x 4 floats) -------
__global__ __launch_bounds__(256) void wprep_kernel(const float* __restrict__ W,
                                                    short* __restrict__ Wbf) {
    const int t = blockIdx.x * 256 + threadIdx.x;   // 0..65535
    const float4 v = *reinterpret_cast<const float4*>(W + (size_t)t * 4);
    short4 s;
    s.x = bf16_rne(v.x); s.y = bf16_rne(v.y);
    s.z = bf16_rne(v.z); s.w = bf16_rne(v.w);
    *reinterpret_cast<short4*>(Wbf + (size_t)t * 4) = s;
}

// Scalar top-3 machinery — STATEMENT MACROS on NAMED SCALARS only.
// (r17-r20: a by-reference helper forced the triples into scratch: 1.2 GB
// spill traffic. Never take these by reference, never index by runtime var.)
#define DECL3(S) \
    float v0_##S = 3.4e38f, v1_##S = 3.4e38f, v2_##S = 3.4e38f; \
    int   i0_##S = 0,       i1_##S = 0,       i2_##S = 0

#define INS3T(S, NV, NI) do {                                            \
    const float _nv = (NV); const int _ni = (NI);                        \
    if (_nv < v0_##S)      { v2_##S = v1_##S; i2_##S = i1_##S;           \
                             v1_##S = v0_##S; i1_##S = i0_##S;           \
                             v0_##S = _nv;    i0_##S = _ni; }            \
    else if (_nv < v1_##S) { v2_##S = v1_##S; i2_##S = i1_##S;           \
                             v1_##S = _nv;    i1_##S = _ni; }            \
    else if (_nv < v2_##S) { v2_##S = _nv;    i2_##S = _ni; }            \
} while (0)

#define MERGE3T(S, M) do {                                               \
    const float _o0 = __shfl_xor(v0_##S, (M));                           \
    const int   _q0 = __shfl_xor(i0_##S, (M));                           \
    const float _o1 = __shfl_xor(v1_##S, (M));                           \
    const int   _q1 = __shfl_xor(i1_##S, (M));                           \
    const float _o2 = __shfl_xor(v2_##S, (M));                           \
    const int   _q2 = __shfl_xor(i2_##S, (M));                           \
    INS3T(S, _o0, _q0);                                                  \
    INS3T(S, _o1, _q1);                                                  \
    INS3T(S, _o2, _q2);                                                  \
} while (0)

// sort the 3 candidate ids ascending and write to cand[R]
#define WRITE3T(S, R) do {                                               \
    int _a = i0_##S, _b = i1_##S, _c = i2_##S, _t;                       \
    if (_a > _b) { _t = _a; _a = _b; _b = _t; }                          \
    if (_b > _c) { _t = _b; _b = _c; _c = _t; }                          \
    if (_a > _b) { _t = _a; _a = _b; _b = _t; }                          \
    cand[R][0] = _a; cand[R][1] = _b; cand[R][2] = _c;                   \
} while (0)

// --- kernel 1: MFMA bf16 screening (LDS B, 2 MFMA per ds_read) -------------
// 128 rows/block, 4 waves; wave w owns 32 rows = TWO 16-row A-frag sets.
// Every B-fragment read feeds 2 MFMAs -> half the ds_read traffic of r22.
// mfma_f32_16x16x32_bf16 C/D: col=lane&15, row=(lane>>4)*4+reg (m89).
__global__ __launch_bounds__(256, 2) void vq_main(
    const float* __restrict__ X, const short* __restrict__ Wbf,
    const float* __restrict__ W, const float* __restrict__ w2g,
    float* __restrict__ out, float* __restrict__ dl)
{
    __shared__ short Wl[64 * WSTR];        // bf16 W tile [code][d]
    __shared__ float w2s[NCODES];
    __shared__ int   cand[MB][3];
    __shared__ int   idx_s[MB];
    __shared__ float rr_x2[MB];
    __shared__ float rr_xw[MB][3];

    const int tid  = threadIdx.x;
    const int lane = tid & 63;
    const int wv   = tid >> 6;
    const int m0   = blockIdx.x * MB;
    const int lg   = lane & 15;            // col-in-frag / row-in-frag
    const int kb   = (lane >> 4) * 8;      // k base within 32-chunk

    for (int i = tid; i < NCODES; i += 256) w2s[i] = w2g[i];

    // A-frags: two 16-row sets, full K=256 (8 frags of 8 bf16 each)
    const int arowA = m0 + wv * 32 + lg;
    const int arowB = arowA + 16;
    short8v aA[8], aB[8];
    #pragma unroll
    for (int kg = 0; kg < 8; ++kg) {
        const float* srcA = X + (size_t)arowA * DD + kg * 32 + kb;
        const float4 xa0 = *reinterpret_cast<const float4*>(srcA);
        const float4 xa1 = *reinterpret_cast<const float4*>(srcA + 4);
        short8v sa;
        sa[0] = bf16_rne(xa0.x); sa[1] = bf16_rne(xa0.y);
        sa[2] = bf16_rne(xa0.z); sa[3] = bf16_rne(xa0.w);
        sa[4] = bf16_rne(xa1.x); sa[5] = bf16_rne(xa1.y);
        sa[6] = bf16_rne(xa1.z); sa[7] = bf16_rne(xa1.w);
        aA[kg] = sa;
        const float* srcB = X + (size_t)arowB * DD + kg * 32 + kb;
        const float4 xb0 = *reinterpret_cast<const float4*>(srcB);
        const float4 xb1 = *reinterpret_cast<const float4*>(srcB + 4);
        short8v sb;
        sb[0] = bf16_rne(xb0.x); sb[1] = bf16_rne(xb0.y);
        sb[2] = bf16_rne(xb0.z); sb[3] = bf16_rne(xb0.w);
        sb[4] = bf16_rne(xb1.x); sb[5] = bf16_rne(xb1.y);
        sb[6] = bf16_rne(xb1.z); sb[7] = bf16_rne(xb1.w);
        aB[kg] = sb;
    }

    // top-3 per owned row-reg: 4 row-regs x 2 sets, named scalars
    DECL3(A0); DECL3(A1); DECL3(A2); DECL3(A3);
    DECL3(B0); DECL3(B1); DECL3(B2); DECL3(B3);

    for (int ct = 0; ct < NCODES / 64; ++ct) {
        const int c0 = ct * 64;
        __syncthreads();   // protect previous tile's readers (and w2s, iter 0)
        // stage bf16 W tile (64 codes x 256 d): pure b128 copy, 8/thread
        #pragma unroll
        for (int l = 0; l < 8; ++l) {
            const int f    = tid + l * 256;   // 0..2047 16B-chunks
            const int code = f >> 5;          // 32 chunks per code
            const int ch   = f & 31;
            const uint4 wv4 = *reinterpret_cast<const uint4*>(
                Wbf + (size_t)(c0 + code) * DD + ch * 8);
            *reinterpret_cast<uint4*>(&Wl[code * WSTR + ch * 8]) = wv4;
        }
        __syncthreads();

        f32x4 accA0 = {0.f,0.f,0.f,0.f}, accA1 = {0.f,0.f,0.f,0.f};
        f32x4 accA2 = {0.f,0.f,0.f,0.f}, accA3 = {0.f,0.f,0.f,0.f};
        f32x4 accB0 = {0.f,0.f,0.f,0.f}, accB1 = {0.f,0.f,0.f,0.f};
        f32x4 accB2 = {0.f,0.f,0.f,0.f}, accB3 = {0.f,0.f,0.f,0.f};

        #pragma unroll
        for (int kg = 0; kg < 8; ++kg) {
            const short8v b0 = *reinterpret_cast<const short8v*>(
                &Wl[(0 * 16 + lg) * WSTR + kg * 32 + kb]);
            const short8v b1 = *reinterpret_cast<const short8v*>(
                &Wl[(1 * 16 + lg) * WSTR + kg * 32 + kb]);
            const short8v b2 = *reinterpret_cast<const short8v*>(
                &Wl[(2 * 16 + lg) * WSTR + kg * 32 + kb]);
            const short8v b3 = *reinterpret_cast<const short8v*>(
                &Wl[(3 * 16 + lg) * WSTR + kg * 32 + kb]);
            accA0 = __builtin_amdgcn_mfma_f32_16x16x32_bf16(aA[kg], b0, accA0, 0, 0, 0);
            accB0 = __builtin_amdgcn_mfma_f32_16x16x32_bf16(aB[kg], b0, accB0, 0, 0, 0);
            accA1 = __builtin_amdgcn_mfma_f32_16x16x32_bf16(aA[kg], b1, accA1, 0, 0, 0);
            accB1 = __builtin_amdgcn_mfma_f32_16x16x32_bf16(aB[kg], b1, accB1, 0, 0, 0);
            accA2 = __builtin_amdgcn_mfma_f32_16x16x32_bf16(aA[kg], b2, accA2, 0, 0, 0);
            accB2 = __builtin_amdgcn_mfma_f32_16x16x32_bf16(aB[kg], b2, accB2, 0, 0, 0);
            accA3 = __builtin_amdgcn_mfma_f32_16x16x32_bf16(aA[kg], b3, accA3, 0, 0, 0);
            accB3 = __builtin_amdgcn_mfma_f32_16x16x32_bf16(aB[kg], b3, accB3, 0, 0, 0);
        }

        // epilogue: dist = w2 - 2*xw, top-3 insert (4 codes x 8 row-regs)
        {
            const int   c   = c0 + 0 * 16 + lg;
            const float w2v = w2s[c];
            INS3T(A0, __builtin_fmaf(-2.f, accA0[0], w2v), c);
            INS3T(A1, __builtin_fmaf(-2.f, accA0[1], w2v), c);
            INS3T(A2, __builtin_fmaf(-2.f, accA0[2], w2v), c);
            INS3T(A3, __builtin_fmaf(-2.f, accA0[3], w2v), c);
            INS3T(B0, __builtin_fmaf(-2.f, accB0[0], w2v), c);
            INS3T(B1, __builtin_fmaf(-2.f, accB0[1], w2v), c);
            INS3T(B2, __builtin_fmaf(-2.f, accB0[2], w2v), c);
            INS3T(B3, __builtin_fmaf(-2.f, accB0[3], w2v), c);
        }
        {
            const int   c   = c0 + 1 * 16 + lg;
            const float w2v = w2s[c];
            INS3T(A0, __builtin_fmaf(-2.f, accA1[0], w2v), c);
            INS3T(A1, __builtin_fmaf(-2.f, accA1[1], w2v), c);
            INS3T(A2, __builtin_fmaf(-2.f, accA1[2], w2v), c);
            INS3T(A3, __builtin_fmaf(-2.f, accA1[3], w2v), c);
            INS3T(B0, __builtin_fmaf(-2.f, accB1[0], w2v), c);
            INS3T(B1, __builtin_fmaf(-2.f, accB1[1], w2v), c);
            INS3T(B2, __builtin_fmaf(-2.f, accB1[2], w2v), c);
            INS3T(B3, __builtin_fmaf(-2.f, accB1[3], w2v), c);
        }
        {
            const int   c   = c0 + 2 * 16 + lg;
            const float w2v = w2s[c];
            INS3T(A0, __builtin_fmaf(-2.f, accA2[0], w2v), c);
            INS3T(A1, __builtin_fmaf(-2.f, accA2[1], w2v), c);
            INS3T(A2, __builtin_fmaf(-2.f, accA2[2], w2v), c);
            INS3T(A3, __builtin_fmaf(-2.f, accA2[3], w2v), c);
            INS3T(B0, __builtin_fmaf(-2.f, accB2[0], w2v), c);
            INS3T(B1, __builtin_fmaf(-2.f, accB2[1], w2v), c);
            INS3T(B2, __builtin_fmaf(-2.f, accB2[2], w2v), c);
            INS3T(B3, __builtin_fmaf(-2.f, accB2[3], w2v), c);
        }
        {
            const int   c   = c0 + 3 * 16 + lg;
            const float w2v = w2s[c];
            INS3T(A0, __builtin_fmaf(-2.f, accA3[0], w2v), c);
            INS3T(A1, __builtin_fmaf(-2.f, accA3[1], w2v), c);
            INS3T(A2, __builtin_fmaf(-2.f, accA3[2], w2v), c);
            INS3T(A3, __builtin_fmaf(-2.f, accA3[3], w2v), c);
            INS3T(B0, __builtin_fmaf(-2.f, accB3[0], w2v), c);
            INS3T(B1, __builtin_fmaf(-2.f, accB3[1], w2v), c);
            INS3T(B2, __builtin_fmaf(-2.f, accB3[2], w2v), c);
            INS3T(B3, __builtin_fmaf(-2.f, accB3[3], w2v), c);
        }
    }

    // shuffle top-3 merge across the 16 candidate lanes (lg) of each group
    #pragma unroll
    for (int m = 1; m <= 8; m <<= 1) {
        MERGE3T(A0, m); MERGE3T(A1, m); MERGE3T(A2, m); MERGE3T(A3, m);
        MERGE3T(B0, m); MERGE3T(B1, m); MERGE3T(B2, m); MERGE3T(B3, m);
    }
    if (lg == 0) {
        const int rbA = wv * 32 + (lane >> 4) * 4;
        WRITE3T(A0, rbA + 0);  WRITE3T(A1, rbA + 1);
        WRITE3T(A2, rbA + 2);  WRITE3T(A3, rbA + 3);
        WRITE3T(B0, rbA + 16); WRITE3T(B1, rbA + 17);
        WRITE3T(B2, rbA + 18); WRITE3T(B3, rbA + 19);
    }
    __syncthreads();

    // parallel bit-exact re-rank (r13 recipe): 2 threads per row
    {
        const int r = tid >> 1;
        const int u = tid & 1;
        const float* xr = X + (size_t)(m0 + r) * DD;
        if (u == 0) {
            rr_x2[r]    = xla_seq_fma_sumsq256(xr);
            rr_xw[r][0] = chain_fma_dot256(xr, W + (size_t)cand[r][0] * DD);
        } else {
            rr_xw[r][1] = chain_fma_dot256(xr, W + (size_t)cand[r][1] * DD);
            rr_xw[r][2] = chain_fma_dot256(xr, W + (size_t)cand[r][2] * DD);
        }
    }
    __syncthreads();

    if (tid < MB) {
#pragma clang fp contract(off)
        const int b0 = cand[tid][0], b1 = cand[tid][1], b2 = cand[tid][2];
        const float x2  = rr_x2[tid];
        const float xw0 = rr_xw[tid][0];
        const float xw1 = rr_xw[tid][1];
        const float xw2 = rr_xw[tid][2];
        const float dd0 = (x2 - 2.0f * xw0) + w2s[b0];
        const float dd1 = (x2 - 2.0f * xw1) + w2s[b1];
        const float dd2 = (x2 - 2.0f * xw2) + w2s[b2];
        int pick = b0; float best = dd0; float pd = xw0;
        if (dd1 < best) { best = dd1; pick = b1; pd = xw1; }
        if (dd2 < best) { best = dd2; pick = b2; pd = xw2; }
        idx_s[tid] = pick;
        dl[m0 + tid] = pd;
    }
    __syncthreads();

    // gather-write quantized rows (coalesced float4)
    const float4* W4 = reinterpret_cast<const float4*>(W);
    float4*       O4 = reinterpret_cast<float4*>(out);
    #pragma unroll
    for (int l = 0; l < 32; ++l) {
        const int e  = tid + l * 256;   // 0..8191
        const int r  = e >> 6;
        const int c4 = e & 63;
        O4[(size_t)(m0 + r) * (DD / 4) + c4] =
            W4[(size_t)idx_s[r] * (DD / 4) + c4];
    }
}

// --- kernel 2a: per-batch softmax sum (8 blocks, one per batch) ------------
__global__ __launch_bounds__(256) void vq_loss_partial(const float* __restrict__ dl,
                                                       float* __restrict__ partial) {
    __shared__ float red[256];
    const int tid = threadIdx.x;
    const int b   = blockIdx.x;
    const float* row = dl + (size_t)b * 8192;

    float lm = -3.4e38f;
    for (int i = tid; i < 8192; i += 256) lm = fmaxf(lm, row[i]);
    red[tid] = lm; __syncthreads();
    for (int s = 128; s > 0; s >>= 1) {
        if (tid < s) red[tid] = fmaxf(red[tid], red[tid + s]);
        __syncthreads();
    }
    const float mx = red[0]; __syncthreads();

    float ls = 0.f;
    for (int i = tid; i < 8192; i += 256) ls += expf(row[i] - mx);
    red[tid] = ls; __syncthreads();
    for (int s = 128; s > 0; s >>= 1) {
        if (tid < s) red[tid] += red[tid + s];
        __syncthreads();
    }
    const float Z = red[0]; __syncthreads();

    float lc = 0.f;
    for (int i = tid; i < 8192; i += 256) lc += expf(row[i] - mx) / Z;
    red[tid] = lc; __syncthreads();
    for (int s = 128; s > 0; s >>= 1) {
        if (tid < s) red[tid] += red[tid + s];
        __syncthreads();
    }
    if (tid == 0) partial[b] = red[0];
}

// --- kernel 2b: final sum of 8 partials ------------------------------------
__global__ void vq_loss_final(const float* __restrict__ partial,
                              float* __restrict__ outv) {
    if (threadIdx.x == 0) {
        float t = 0.f;
        for (int b = 0; b < 8; ++b) t += partial[b];
        outv[0] = t;
    }
}

// --- launch ----------------------------------------------------------------
extern "C" void kernel_launch(void* const* d_in, const int* in_sizes, int n_in,
                              void* d_out, int out_size, void* d_ws, size_t ws_size,
                              hipStream_t stream) {
    const float* X = (const float*)d_in[0];   // latents  [8,8192,256] f32
    const float* W = (const float*)d_in[1];   // weights  [1024,256]   f32
    float* out = (float*)d_out;               // quantized (65536*256) + vq_loss
    float* w2      = (float*)d_ws;            // [1024]  XLA-replica code norms
    float* dlv     = w2 + NCODES;             // [65536] dot at argmin
    float* partial = dlv + MTOT;              // [8]     per-batch loss
    short* Wbf     = (short*)(partial + 8);   // [1024*256] bf16 codebook

    w2_kernel      <<<NCODES / 256,            256, 0, stream>>>(W, w2);
    wprep_kernel   <<<NCODES * DD / 4 / 256,   256, 0, stream>>>(W, Wbf);  // 256 blocks
    vq_main        <<<MTOT / MB,               256, 0, stream>>>(X, Wbf, W, w2, out, dlv);
    vq_loss_partial<<<8,                       256, 0, stream>>>(dlv, partial);
    vq_loss_final  <<<1,                        64, 0, stream>>>(partial, out + (size_t)MTOT * DD);
}

// Round 24
// 168.133 us; speedup vs baseline: 3.1897x; 1.0960x over previous
//
#include <hip/hip_runtime.h>
#include <cstddef>

#define DD     256      // feature dim
#define NCODES 1024     // codebook size
#define MTOT   65536    // 8*8192 queries
#define MB     128      // rows per block (512 blocks); each wave owns 32 rows
#define WSTR   264      // Wl LDS row stride in bf16 units (256 + 8 pad)

typedef __attribute__((ext_vector_type(8))) short short8v;  // 8 bf16 (4 VGPR)
typedef __attribute__((ext_vector_type(4))) float f32x4;    // MFMA accum

// ====== XLA:CPU f32 replica helpers (DO NOT TOUCH — verified r13) ==========
__device__ __forceinline__ float xla_seq_fma_sumsq256(const float* __restrict__ a) {
    float acc = 0.f;
    #pragma unroll 8
    for (int d = 0; d < 256; ++d)
        acc = __builtin_fmaf(a[d], a[d], acc);
    return acc;
}

__device__ __forceinline__ float chain_fma_dot256(const float* __restrict__ x,
                                                  const float* __restrict__ w) {
    float acc = 0.f;
    #pragma unroll 8
    for (int d = 0; d < 256; ++d)
        acc = __builtin_fmaf(x[d], w[d], acc);
    return acc;
}

// ====== bf16 helpers (screening only) ======================================
__device__ __forceinline__ short bf16_rne(float f) {
    unsigned u = __builtin_bit_cast(unsigned, f);
    u = u + 0x7FFFu + ((u >> 16) & 1u);
    return (short)(u >> 16);
}

// --- kernel 0: fused W->bf16 conversion + per-code norms -------------------
// 256 blocks x 256 threads; block b converts codes 4b..4b+3 (1024 floats);
// threads 0..3 additionally compute the XLA-replica w2 for those codes.
__global__ __launch_bounds__(256) void wprep_w2_kernel(const float* __restrict__ W,
                                                       short* __restrict__ Wbf,
                                                       float* __restrict__ w2) {
    const int t = blockIdx.x * 256 + threadIdx.x;   // 0..65535 float4 slots
    const float4 v = *reinterpret_cast<const float4*>(W + (size_t)t * 4);
    short4 s;
    s.x = bf16_rne(v.x); s.y = bf16_rne(v.y);
    s.z = bf16_rne(v.z); s.w = bf16_rne(v.w);
    *reinterpret_cast<short4*>(Wbf + (size_t)t * 4) = s;
    if (threadIdx.x < 4) {
        const int c = blockIdx.x * 4 + threadIdx.x;
        w2[c] = xla_seq_fma_sumsq256(W + (size_t)c * DD);
    }
}

// Scalar top-3 machinery — STATEMENT MACROS on NAMED SCALARS only.
// (r17-r20: a by-reference helper forced the triples into scratch: 1.2 GB
// spill traffic. Never take these by reference, never index by runtime var.)
#define DECL3(S) \
    float v0_##S = 3.4e38f, v1_##S = 3.4e38f, v2_##S = 3.4e38f; \
    int   i0_##S = 0,       i1_##S = 0,       i2_##S = 0

#define INS3T(S, NV, NI) do {                                            \
    const float _nv = (NV); const int _ni = (NI);                        \
    if (_nv < v0_##S)      { v2_##S = v1_##S; i2_##S = i1_##S;           \
                             v1_##S = v0_##S; i1_##S = i0_##S;           \
                             v0_##S = _nv;    i0_##S = _ni; }            \
    else if (_nv < v1_##S) { v2_##S = v1_##S; i2_##S = i1_##S;           \
                             v1_##S = _nv;    i1_##S = _ni; }            \
    else if (_nv < v2_##S) { v2_##S = _nv;    i2_##S = _ni; }            \
} while (0)

#define MERGE3T(S, M) do {                                               \
    const float _o0 = __shfl_xor(v0_##S, (M));                           \
    const int   _q0 = __shfl_xor(i0_##S, (M));                           \
    const float _o1 = __shfl_xor(v1_##S, (M));                           \
    const int   _q1 = __shfl_xor(i1_##S, (M));                           \
    const float _o2 = __shfl_xor(v2_##S, (M));                           \
    const int   _q2 = __shfl_xor(i2_##S, (M));                           \
    INS3T(S, _o0, _q0);                                                  \
    INS3T(S, _o1, _q1);                                                  \
    INS3T(S, _o2, _q2);                                                  \
} while (0)

// sort the 3 candidate ids ascending and write to cand[R]
#define WRITE3T(S, R) do {                                               \
    int _a = i0_##S, _b = i1_##S, _c = i2_##S, _t;                       \
    if (_a > _b) { _t = _a; _a = _b; _b = _t; }                          \
    if (_b > _c) { _t = _b; _b = _c; _c = _t; }                          \
    if (_a > _b) { _t = _a; _a = _b; _b = _t; }                          \
    cand[R][0] = _a; cand[R][1] = _b; cand[R][2] = _c;                   \
} while (0)

// --- kernel 1: MFMA bf16 screening, double-buffered single-barrier pipeline
// 128 rows/block, 4 waves; wave owns 32 rows (2 A-frag sets, 2 MFMA/ds_read).
// Per tile: issue next tile's 8 global loads -> compute current from LDS ->
// ds_write prefetch into the OTHER buffer -> one barrier. Global L2 latency
// hides under compute; one barrier/tile instead of two.
// mfma_f32_16x16x32_bf16 C/D: col=lane&15, row=(lane>>4)*4+reg (m89).
__global__ __launch_bounds__(256, 2) void vq_main(
    const float* __restrict__ X, const short* __restrict__ Wbf,
    const float* __restrict__ W, const float* __restrict__ w2g,
    float* __restrict__ out, float* __restrict__ dl)
{
    __shared__ short Wl[2][64 * WSTR];     // double-buffered bf16 W tile
    __shared__ float w2s[NCODES];
    __shared__ int   cand[MB][3];
    __shared__ int   idx_s[MB];
    __shared__ float rr_x2[MB];
    __shared__ float rr_xw[MB][3];

    const int tid  = threadIdx.x;
    const int lane = tid & 63;
    const int wv   = tid >> 6;
    const int m0   = blockIdx.x * MB;
    const int lg   = lane & 15;            // col-in-frag / row-in-frag
    const int kb   = (lane >> 4) * 8;      // k base within 32-chunk

    for (int i = tid; i < NCODES; i += 256) w2s[i] = w2g[i];

    // staging geometry (loop-invariant per chunk L)
    const int code0 = (tid +   0) >> 5, ch0 = (tid +   0) & 31;
    const int code1 = (tid + 256) >> 5, ch1 = (tid + 256) & 31;
    const int code2 = (tid + 512) >> 5, ch2 = (tid + 512) & 31;
    const int code3 = (tid + 768) >> 5, ch3 = (tid + 768) & 31;
    const int code4 = (tid +1024) >> 5, ch4 = (tid +1024) & 31;
    const int code5 = (tid +1280) >> 5, ch5 = (tid +1280) & 31;
    const int code6 = (tid +1536) >> 5, ch6 = (tid +1536) & 31;
    const int code7 = (tid +1792) >> 5, ch7 = (tid +1792) & 31;
    const size_t so0 = (size_t)code0 * DD + ch0 * 8;
    const size_t so1 = (size_t)code1 * DD + ch1 * 8;
    const size_t so2 = (size_t)code2 * DD + ch2 * 8;
    const size_t so3 = (size_t)code3 * DD + ch3 * 8;
    const size_t so4 = (size_t)code4 * DD + ch4 * 8;
    const size_t so5 = (size_t)code5 * DD + ch5 * 8;
    const size_t so6 = (size_t)code6 * DD + ch6 * 8;
    const size_t so7 = (size_t)code7 * DD + ch7 * 8;
    const int do0 = code0 * WSTR + ch0 * 8;
    const int do1 = code1 * WSTR + ch1 * 8;
    const int do2 = code2 * WSTR + ch2 * 8;
    const int do3 = code3 * WSTR + ch3 * 8;
    const int do4 = code4 * WSTR + ch4 * 8;
    const int do5 = code5 * WSTR + ch5 * 8;
    const int do6 = code6 * WSTR + ch6 * 8;
    const int do7 = code7 * WSTR + ch7 * 8;

    // A-frags: two 16-row sets, full K=256 (8 frags of 8 bf16 each)
    const int arowA = m0 + wv * 32 + lg;
    const int arowB = arowA + 16;
    short8v aA[8], aB[8];
    #pragma unroll
    for (int kg = 0; kg < 8; ++kg) {
        const float* srcA = X + (size_t)arowA * DD + kg * 32 + kb;
        const float4 xa0 = *reinterpret_cast<const float4*>(srcA);
        const float4 xa1 = *reinterpret_cast<const float4*>(srcA + 4);
        short8v sa;
        sa[0] = bf16_rne(xa0.x); sa[1] = bf16_rne(xa0.y);
        sa[2] = bf16_rne(xa0.z); sa[3] = bf16_rne(xa0.w);
        sa[4] = bf16_rne(xa1.x); sa[5] = bf16_rne(xa1.y);
        sa[6] = bf16_rne(xa1.z); sa[7] = bf16_rne(xa1.w);
        aA[kg] = sa;
        const float* srcB = X + (size_t)arowB * DD + kg * 32 + kb;
        const float4 xb0 = *reinterpret_cast<const float4*>(srcB);
        const float4 xb1 = *reinterpret_cast<const float4*>(srcB + 4);
        short8v sb;
        sb[0] = bf16_rne(xb0.x); sb[1] = bf16_rne(xb0.y);
        sb[2] = bf16_rne(xb0.z); sb[3] = bf16_rne(xb0.w);
        sb[4] = bf16_rne(xb1.x); sb[5] = bf16_rne(xb1.y);
        sb[6] = bf16_rne(xb1.z); sb[7] = bf16_rne(xb1.w);
        aB[kg] = sb;
    }

    // top-3 per owned row-reg: 4 row-regs x 2 sets, named scalars
    DECL3(A0); DECL3(A1); DECL3(A2); DECL3(A3);
    DECL3(B0); DECL3(B1); DECL3(B2); DECL3(B3);

    // prologue: stage tile 0 into buf 0
    {
        const short* base = Wbf;   // tile 0
        const uint4 p0 = *reinterpret_cast<const uint4*>(base + so0);
        const uint4 p1 = *reinterpret_cast<const uint4*>(base + so1);
        const uint4 p2 = *reinterpret_cast<const uint4*>(base + so2);
        const uint4 p3 = *reinterpret_cast<const uint4*>(base + so3);
        const uint4 p4 = *reinterpret_cast<const uint4*>(base + so4);
        const uint4 p5 = *reinterpret_cast<const uint4*>(base + so5);
        const uint4 p6 = *reinterpret_cast<const uint4*>(base + so6);
        const uint4 p7 = *reinterpret_cast<const uint4*>(base + so7);
        *reinterpret_cast<uint4*>(&Wl[0][do0]) = p0;
        *reinterpret_cast<uint4*>(&Wl[0][do1]) = p1;
        *reinterpret_cast<uint4*>(&Wl[0][do2]) = p2;
        *reinterpret_cast<uint4*>(&Wl[0][do3]) = p3;
        *reinterpret_cast<uint4*>(&Wl[0][do4]) = p4;
        *reinterpret_cast<uint4*>(&Wl[0][do5]) = p5;
        *reinterpret_cast<uint4*>(&Wl[0][do6]) = p6;
        *reinterpret_cast<uint4*>(&Wl[0][do7]) = p7;
    }
    __syncthreads();

    for (int ct = 0; ct < NCODES / 64; ++ct) {
        const int cur = ct & 1;
        const int c0  = ct * 64;
        const bool pfv = (ct < NCODES / 64 - 1);

        // issue next tile's loads FIRST (latency hides under compute)
        uint4 p0, p1, p2, p3, p4, p5, p6, p7;
        if (pfv) {
            const short* base = Wbf + (size_t)(c0 + 64) * DD;
            p0 = *reinterpret_cast<const uint4*>(base + so0);
            p1 = *reinterpret_cast<const uint4*>(base + so1);
            p2 = *reinterpret_cast<const uint4*>(base + so2);
            p3 = *reinterpret_cast<const uint4*>(base + so3);
            p4 = *reinterpret_cast<const uint4*>(base + so4);
            p5 = *reinterpret_cast<const uint4*>(base + so5);
            p6 = *reinterpret_cast<const uint4*>(base + so6);
            p7 = *reinterpret_cast<const uint4*>(base + so7);
        }

        const short* wl = Wl[cur];

        f32x4 accA0 = {0.f,0.f,0.f,0.f}, accA1 = {0.f,0.f,0.f,0.f};
        f32x4 accA2 = {0.f,0.f,0.f,0.f}, accA3 = {0.f,0.f,0.f,0.f};
        f32x4 accB0 = {0.f,0.f,0.f,0.f}, accB1 = {0.f,0.f,0.f,0.f};
        f32x4 accB2 = {0.f,0.f,0.f,0.f}, accB3 = {0.f,0.f,0.f,0.f};

        #pragma unroll
        for (int kg = 0; kg < 8; ++kg) {
            const short8v b0 = *reinterpret_cast<const short8v*>(
                &wl[(0 * 16 + lg) * WSTR + kg * 32 + kb]);
            const short8v b1 = *reinterpret_cast<const short8v*>(
                &wl[(1 * 16 + lg) * WSTR + kg * 32 + kb]);
            const short8v b2 = *reinterpret_cast<const short8v*>(
                &wl[(2 * 16 + lg) * WSTR + kg * 32 + kb]);
            const short8v b3 = *reinterpret_cast<const short8v*>(
                &wl[(3 * 16 + lg) * WSTR + kg * 32 + kb]);
            accA0 = __builtin_amdgcn_mfma_f32_16x16x32_bf16(aA[kg], b0, accA0, 0, 0, 0);
            accB0 = __builtin_amdgcn_mfma_f32_16x16x32_bf16(aB[kg], b0, accB0, 0, 0, 0);
            accA1 = __builtin_amdgcn_mfma_f32_16x16x32_bf16(aA[kg], b1, accA1, 0, 0, 0);
            accB1 = __builtin_amdgcn_mfma_f32_16x16x32_bf16(aB[kg], b1, accB1, 0, 0, 0);
            accA2 = __builtin_amdgcn_mfma_f32_16x16x32_bf16(aA[kg], b2, accA2, 0, 0, 0);
            accB2 = __builtin_amdgcn_mfma_f32_16x16x32_bf16(aB[kg], b2, accB2, 0, 0, 0);
            accA3 = __builtin_amdgcn_mfma_f32_16x16x32_bf16(aA[kg], b3, accA3, 0, 0, 0);
            accB3 = __builtin_amdgcn_mfma_f32_16x16x32_bf16(aB[kg], b3, accB3, 0, 0, 0);
        }

        // epilogue: dist = w2 - 2*xw, top-3 insert (4 codes x 8 row-regs)
        {
            const int   c   = c0 + 0 * 16 + lg;
            const float w2v = w2s[c];
            INS3T(A0, __builtin_fmaf(-2.f, accA0[0], w2v), c);
            INS3T(A1, __builtin_fmaf(-2.f, accA0[1], w2v), c);
            INS3T(A2, __builtin_fmaf(-2.f, accA0[2], w2v), c);
            INS3T(A3, __builtin_fmaf(-2.f, accA0[3], w2v), c);
            INS3T(B0, __builtin_fmaf(-2.f, accB0[0], w2v), c);
            INS3T(B1, __builtin_fmaf(-2.f, accB0[1], w2v), c);
            INS3T(B2, __builtin_fmaf(-2.f, accB0[2], w2v), c);
            INS3T(B3, __builtin_fmaf(-2.f, accB0[3], w2v), c);
        }
        {
            const int   c   = c0 + 1 * 16 + lg;
            const float w2v = w2s[c];
            INS3T(A0, __builtin_fmaf(-2.f, accA1[0], w2v), c);
            INS3T(A1, __builtin_fmaf(-2.f, accA1[1], w2v), c);
            INS3T(A2, __builtin_fmaf(-2.f, accA1[2], w2v), c);
            INS3T(A3, __builtin_fmaf(-2.f, accA1[3], w2v), c);
            INS3T(B0, __builtin_fmaf(-2.f, accB1[0], w2v), c);
            INS3T(B1, __builtin_fmaf(-2.f, accB1[1], w2v), c);
            INS3T(B2, __builtin_fmaf(-2.f, accB1[2], w2v), c);
            INS3T(B3, __builtin_fmaf(-2.f, accB1[3], w2v), c);
        }
        {
            const int   c   = c0 + 2 * 16 + lg;
            const float w2v = w2s[c];
            INS3T(A0, __builtin_fmaf(-2.f, accA2[0], w2v), c);
            INS3T(A1, __builtin_fmaf(-2.f, accA2[1], w2v), c);
            INS3T(A2, __builtin_fmaf(-2.f, accA2[2], w2v), c);
            INS3T(A3, __builtin_fmaf(-2.f, accA2[3], w2v), c);
            INS3T(B0, __builtin_fmaf(-2.f, accB2[0], w2v), c);
            INS3T(B1, __builtin_fmaf(-2.f, accB2[1], w2v), c);
            INS3T(B2, __builtin_fmaf(-2.f, accB2[2], w2v), c);
            INS3T(B3, __builtin_fmaf(-2.f, accB2[3], w2v), c);
        }
        {
            const int   c   = c0 + 3 * 16 + lg;
            const float w2v = w2s[c];
            INS3T(A0, __builtin_fmaf(-2.f, accA3[0], w2v), c);
            INS3T(A1, __builtin_fmaf(-2.f, accA3[1], w2v), c);
            INS3T(A2, __builtin_fmaf(-2.f, accA3[2], w2v), c);
            INS3T(A3, __builtin_fmaf(-2.f, accA3[3], w2v), c);
            INS3T(B0, __builtin_fmaf(-2.f, accB3[0], w2v), c);
            INS3T(B1, __builtin_fmaf(-2.f, accB3[1], w2v), c);
            INS3T(B2, __builtin_fmaf(-2.f, accB3[2], w2v), c);
            INS3T(B3, __builtin_fmaf(-2.f, accB3[3], w2v), c);
        }

        // write prefetched tile into the OTHER buffer (readers done with it
        // since last barrier; no conflict with current readers)
        if (pfv) {
            short* wn = Wl[cur ^ 1];
            *reinterpret_cast<uint4*>(&wn[do0]) = p0;
            *reinterpret_cast<uint4*>(&wn[do1]) = p1;
            *reinterpret_cast<uint4*>(&wn[do2]) = p2;
            *reinterpret_cast<uint4*>(&wn[do3]) = p3;
            *reinterpret_cast<uint4*>(&wn[do4]) = p4;
            *reinterpret_cast<uint4*>(&wn[do5]) = p5;
            *reinterpret_cast<uint4*>(&wn[do6]) = p6;
            *reinterpret_cast<uint4*>(&wn[do7]) = p7;
        }
        __syncthreads();
    }

    // shuffle top-3 merge across the 16 candidate lanes (lg) of each group
    #pragma unroll
    for (int m = 1; m <= 8; m <<= 1) {
        MERGE3T(A0, m); MERGE3T(A1, m); MERGE3T(A2, m); MERGE3T(A3, m);
        MERGE3T(B0, m); MERGE3T(B1, m); MERGE3T(B2, m); MERGE3T(B3, m);
    }
    if (lg == 0) {
        const int rbA = wv * 32 + (lane >> 4) * 4;
        WRITE3T(A0, rbA + 0);  WRITE3T(A1, rbA + 1);
        WRITE3T(A2, rbA + 2);  WRITE3T(A3, rbA + 3);
        WRITE3T(B0, rbA + 16); WRITE3T(B1, rbA + 17);
        WRITE3T(B2, rbA + 18); WRITE3T(B3, rbA + 19);
    }
    __syncthreads();

    // parallel bit-exact re-rank (r13 recipe): 2 threads per row
    {
        const int r = tid >> 1;
        const int u = tid & 1;
        const float* xr = X + (size_t)(m0 + r) * DD;
        if (u == 0) {
            rr_x2[r]    = xla_seq_fma_sumsq256(xr);
            rr_xw[r][0] = chain_fma_dot256(xr, W + (size_t)cand[r][0] * DD);
        } else {
            rr_xw[r][1] = chain_fma_dot256(xr, W + (size_t)cand[r][1] * DD);
            rr_xw[r][2] = chain_fma_dot256(xr, W + (size_t)cand[r][2] * DD);
        }
    }
    __syncthreads();

    if (tid < MB) {
#pragma clang fp contract(off)
        const int b0 = cand[tid][0], b1 = cand[tid][1], b2 = cand[tid][2];
        const float x2  = rr_x2[tid];
        const float xw0 = rr_xw[tid][0];
        const float xw1 = rr_xw[tid][1];
        const float xw2 = rr_xw[tid][2];
        const float dd0 = (x2 - 2.0f * xw0) + w2s[b0];
        const float dd1 = (x2 - 2.0f * xw1) + w2s[b1];
        const float dd2 = (x2 - 2.0f * xw2) + w2s[b2];
        int pick = b0; float best = dd0; float pd = xw0;
        if (dd1 < best) { best = dd1; pick = b1; pd = xw1; }
        if (dd2 < best) { best = dd2; pick = b2; pd = xw2; }
        idx_s[tid] = pick;
        dl[m0 + tid] = pd;
    }
    __syncthreads();

    // gather-write quantized rows (coalesced float4)
    const float4* W4 = reinterpret_cast<const float4*>(W);
    float4*       O4 = reinterpret_cast<float4*>(out);
    #pragma unroll
    for (int l = 0; l < 32; ++l) {
        const int e  = tid + l * 256;   // 0..8191
        const int r  = e >> 6;
        const int c4 = e & 63;
        O4[(size_t)(m0 + r) * (DD / 4) + c4] =
            W4[(size_t)idx_s[r] * (DD / 4) + c4];
    }
}

// --- kernel 2a: per-batch softmax sum (8 blocks, one per batch) ------------
__global__ __launch_bounds__(256) void vq_loss_partial(const float* __restrict__ dl,
                                                       float* __restrict__ partial) {
    __shared__ float red[256];
    const int tid = threadIdx.x;
    const int b   = blockIdx.x;
    const float* row = dl + (size_t)b * 8192;

    float lm = -3.4e38f;
    for (int i = tid; i < 8192; i += 256) lm = fmaxf(lm, row[i]);
    red[tid] = lm; __syncthreads();
    for (int s = 128; s > 0; s >>= 1) {
        if (tid < s) red[tid] = fmaxf(red[tid], red[tid + s]);
        __syncthreads();
    }
    const float mx = red[0]; __syncthreads();

    float ls = 0.f;
    for (int i = tid; i < 8192; i += 256) ls += expf(row[i] - mx);
    red[tid] = ls; __syncthreads();
    for (int s = 128; s > 0; s >>= 1) {
        if (tid < s) red[tid] += red[tid + s];
        __syncthreads();
    }
    const float Z = red[0]; __syncthreads();

    float lc = 0.f;
    for (int i = tid; i < 8192; i += 256) lc += expf(row[i] - mx) / Z;
    red[tid] = lc; __syncthreads();
    for (int s = 128; s > 0; s >>= 1) {
        if (tid < s) red[tid] += red[tid + s];
        __syncthreads();
    }
    if (tid == 0) partial[b] = red[0];
}

// --- kernel 2b: final sum of 8 partials ------------------------------------
__global__ void vq_loss_final(const float* __restrict__ partial,
                              float* __restrict__ outv) {
    if (threadIdx.x == 0) {
        float t = 0.f;
        for (int b = 0; b < 8; ++b) t += partial[b];
        outv[0] = t;
    }
}

// --- launch ----------------------------------------------------------------
extern "C" void kernel_launch(void* const* d_in, const int* in_sizes, int n_in,
                              void* d_out, int out_size, void* d_ws, size_t ws_size,
                              hipStream_t stream) {
    const float* X = (const float*)d_in[0];   // latents  [8,8192,256] f32
    const float* W = (const float*)d_in[1];   // weights  [1024,256]   f32
    float* out = (float*)d_out;               // quantized (65536*256) + vq_loss
    float* w2      = (float*)d_ws;            // [1024]  XLA-replica code norms
    float* dlv     = w2 + NCODES;             // [65536] dot at argmin
    float* partial = dlv + MTOT;              // [8]     per-batch loss
    short* Wbf     = (short*)(partial + 8);   // [1024*256] bf16 codebook

    wprep_w2_kernel<<<NCODES * DD / 4 / 256, 256, 0, stream>>>(W, Wbf, w2);
    vq_main        <<<MTOT / MB,             256, 0, stream>>>(X, Wbf, W, w2, out, dlv);
    vq_loss_partial<<<8,                     256, 0, stream>>>(dlv, partial);
    vq_loss_final  <<<1,                      64, 0, stream>>>(partial, out + (size_t)MTOT * DD);
}